// Round 6
// baseline (322.869 us; speedup 1.0000x reference)
//
#include <hip/hip_runtime.h>
#include <hip/hip_bf16.h>
#include <math.h>

typedef __attribute__((ext_vector_type(8))) short short8;
typedef __attribute__((ext_vector_type(4))) float f32x4;
typedef unsigned short ushort_t;

__device__ __forceinline__ ushort_t f2bf(float f) {
    union { float f; unsigned u; } v; v.f = f;
    unsigned r = v.u + 0x7FFF + ((v.u >> 16) & 1);
    return (ushort_t)(r >> 16);
}
__device__ __forceinline__ float bf2f(short s) {
    union { unsigned u; float f; } v; v.u = ((unsigned)(ushort_t)s) << 16;
    return v.f;
}

// ---------------- fp32 -> bf16 convert (x) ----------------
__global__ void cvt_kernel(const float* __restrict__ src, ushort_t* __restrict__ dst, int n8) {
    int i = blockIdx.x * blockDim.x + threadIdx.x;
    int stride = gridDim.x * blockDim.x;
    for (; i < n8; i += stride) {
        const float4* s = reinterpret_cast<const float4*>(src) + (size_t)i * 2;
        float4 a = s[0], b = s[1];
        short8 o;
        o[0] = (short)f2bf(a.x); o[1] = (short)f2bf(a.y);
        o[2] = (short)f2bf(a.z); o[3] = (short)f2bf(a.w);
        o[4] = (short)f2bf(b.x); o[5] = (short)f2bf(b.y);
        o[6] = (short)f2bf(b.z); o[7] = (short)f2bf(b.w);
        reinterpret_cast<short8*>(dst)[i] = o;
    }
}

// ---------------- fused weight convert: wq|wk|wv|wo -> contiguous bf16 ----------------
__global__ void cvtw_kernel(const float* __restrict__ w0, const float* __restrict__ w1,
                            const float* __restrict__ w2, const float* __restrict__ w3,
                            ushort_t* __restrict__ dst, int dd8) {
    int i = blockIdx.x * blockDim.x + threadIdx.x;
    int stride = gridDim.x * blockDim.x;
    const int total = dd8 * 4;
    for (; i < total; i += stride) {
        int which = i / dd8;
        int off = i - which * dd8;
        const float* src = (which == 0) ? w0 : (which == 1) ? w1 : (which == 2) ? w2 : w3;
        const float4* s = reinterpret_cast<const float4*>(src) + (size_t)off * 2;
        float4 a = s[0], b = s[1];
        short8 o;
        o[0] = (short)f2bf(a.x); o[1] = (short)f2bf(a.y);
        o[2] = (short)f2bf(a.z); o[3] = (short)f2bf(a.w);
        o[4] = (short)f2bf(b.x); o[5] = (short)f2bf(b.y);
        o[6] = (short)f2bf(b.z); o[7] = (short)f2bf(b.w);
        reinterpret_cast<short8*>(dst)[i] = o;
    }
}

// ============ 256x256 8-phase GEMM (QKV): BK=64, 8 waves, counted-vmcnt pipeline ============
// LDS: A,B each 2buf x 2half x [128 rows][64 cols] bf16 = 64KB -> 128KB dynamic.
// Swizzle: 16B-slot-in-row ^= (row&7); linear gload_lds dest + inverse-swizzled global src
// + swizzled ds_read (rule #21 correct form). Per-wave 128x64 out = acc[8][4].
// Phase plan per tile U (buffer b=U&1):
//   P1: dsread A-mh0(8)+B-nh0(4); stage A(U+1,h1); MFMA Q00
//   P2: dsread B-nh1(4);                            MFMA Q01
//   P3: dsread A-mh1(8); stage B(U+2,h0);           MFMA Q11
//   P4: stage A(U+2,h0)+B(U+2,h1);                  MFMA Q10; vmcnt(6|0); barrier
// Residency: tile T fully staged >=3 phases before T.P1; vmcnt(6) at T-1.P4 leaves exactly
// the 3 newest half-tiles (6 loads) in flight => tile T resident. vmcnt(0) only at U=nt-2.
__global__ __launch_bounds__(512, 2) void gemm256_qkv(const ushort_t* __restrict__ A,
                                                      const ushort_t* __restrict__ Bw,
                                                      ushort_t* __restrict__ Cout,
                                                      int M, int N, int K) {
    extern __shared__ __align__(16) ushort_t lds[];
    ushort_t* As = lds;              // 32768 elems
    ushort_t* Bs = lds + 32768;
    const int t = threadIdx.x;
    const int wid = t >> 6, lane = t & 63;
    const int wr = wid >> 2, wc = wid & 3;
    const int lr = lane & 15, lg = lane >> 4;

    const int ntc = N >> 8;
    const int nwg = (M >> 8) * ntc;
    const int bid = blockIdx.y * gridDim.x + blockIdx.x;
    const int cpx = nwg >> 3;
    const int swz = (bid & 7) * cpx + (bid >> 3);
    const int m0 = (swz / ntc) * 256, n0 = (swz % ntc) * 256;

    f32x4 acc[8][4] = {};

    // staging source: thread t covers linear LDS 16B-slots {t, t+512} of each half;
    // slot s -> row=s>>3, colslot=(s&7)^(row&7)  (r1=r0+64 keeps same colslot)
    const int r0 = t >> 3;
    const int c0 = (t & 7) ^ (r0 & 7);
    const ushort_t* gA = A + (long)(m0 + r0) * K + c0 * 8;
    const ushort_t* gB = Bw + (long)(n0 + r0) * K + c0 * 8;

    // swizzled ds_read offsets (elements within a 128x64 half)
    int aoffE[2];
    aoffE[0] = lr * 64 + (((0 + lg) ^ (lr & 7)) << 3);
    aoffE[1] = lr * 64 + (((4 + lg) ^ (lr & 7)) << 3);

    const int nt = K >> 6;

#define STAGE_A(X, h) do { const int p_ = (X) & 1;                                             \
    __builtin_amdgcn_global_load_lds((const __attribute__((address_space(1))) unsigned int*)   \
        (gA + (long)((h) * 128) * K + (X) * 64),                                               \
        (__attribute__((address_space(3))) unsigned int*)(As + (p_ * 2 + (h)) * 8192 + t * 8), \
        16, 0, 0);                                                                             \
    __builtin_amdgcn_global_load_lds((const __attribute__((address_space(1))) unsigned int*)   \
        (gA + (long)((h) * 128 + 64) * K + (X) * 64),                                          \
        (__attribute__((address_space(3))) unsigned int*)(As + (p_ * 2 + (h)) * 8192 + 4096 + t * 8), \
        16, 0, 0); } while (0)

#define STAGE_B(X, h) do { const int p_ = (X) & 1;                                             \
    __builtin_amdgcn_global_load_lds((const __attribute__((address_space(1))) unsigned int*)   \
        (gB + (long)((h) * 128) * K + (X) * 64),                                               \
        (__attribute__((address_space(3))) unsigned int*)(Bs + (p_ * 2 + (h)) * 8192 + t * 8), \
        16, 0, 0);                                                                             \
    __builtin_amdgcn_global_load_lds((const __attribute__((address_space(1))) unsigned int*)   \
        (gB + (long)((h) * 128 + 64) * K + (X) * 64),                                          \
        (__attribute__((address_space(3))) unsigned int*)(Bs + (p_ * 2 + (h)) * 8192 + 4096 + t * 8), \
        16, 0, 0); } while (0)

    // prologue: tile0 fully (8 loads) then 3 halves of tile1 (6 loads); wait tile0
    STAGE_A(0, 0); STAGE_A(0, 1); STAGE_B(0, 0); STAGE_B(0, 1);
    STAGE_A(1, 0); STAGE_B(1, 0); STAGE_B(1, 1);
    asm volatile("s_waitcnt vmcnt(6)" ::: "memory");
    __builtin_amdgcn_s_barrier();

    short8 ar[4][2], br0[2][2], br1[2][2];

    for (int U = 0; U < nt; ++U) {
        const int b = U & 1;
        const int Asb = (b * 2 + wr) * 8192;
        const int Bcb = (b * 2 + (wc >> 1)) * 8192 + (wc & 1) * 4096;

        // ---- P1: A-mh0 + B-nh0; stage A(U+1,h1); MFMA Q00
        #pragma unroll
        for (int m = 0; m < 4; ++m)
            #pragma unroll
            for (int ks = 0; ks < 2; ++ks)
                ar[m][ks] = *reinterpret_cast<const short8*>(&As[Asb + m * 1024 + aoffE[ks]]);
        #pragma unroll
        for (int n = 0; n < 2; ++n)
            #pragma unroll
            for (int ks = 0; ks < 2; ++ks)
                br0[n][ks] = *reinterpret_cast<const short8*>(&Bs[Bcb + n * 1024 + aoffE[ks]]);
        if (U + 1 < nt) STAGE_A(U + 1, 1);
        asm volatile("" ::: "memory");
        __builtin_amdgcn_s_barrier();
        __builtin_amdgcn_s_setprio(1);
        #pragma unroll
        for (int m = 0; m < 4; ++m)
            #pragma unroll
            for (int n = 0; n < 2; ++n)
                #pragma unroll
                for (int ks = 0; ks < 2; ++ks)
                    acc[m][n] = __builtin_amdgcn_mfma_f32_16x16x32_bf16(ar[m][ks], br0[n][ks], acc[m][n], 0, 0, 0);
        __builtin_amdgcn_s_setprio(0);
        asm volatile("" ::: "memory");
        __builtin_amdgcn_s_barrier();

        // ---- P2: B-nh1; MFMA Q01
        #pragma unroll
        for (int n = 0; n < 2; ++n)
            #pragma unroll
            for (int ks = 0; ks < 2; ++ks)
                br1[n][ks] = *reinterpret_cast<const short8*>(&Bs[Bcb + 2048 + n * 1024 + aoffE[ks]]);
        asm volatile("" ::: "memory");
        __builtin_amdgcn_s_barrier();
        __builtin_amdgcn_s_setprio(1);
        #pragma unroll
        for (int m = 0; m < 4; ++m)
            #pragma unroll
            for (int n = 0; n < 2; ++n)
                #pragma unroll
                for (int ks = 0; ks < 2; ++ks)
                    acc[m][2 + n] = __builtin_amdgcn_mfma_f32_16x16x32_bf16(ar[m][ks], br1[n][ks], acc[m][2 + n], 0, 0, 0);
        __builtin_amdgcn_s_setprio(0);
        asm volatile("" ::: "memory");
        __builtin_amdgcn_s_barrier();

        // ---- P3: A-mh1; stage B(U+2,h0); MFMA Q11
        #pragma unroll
        for (int m = 0; m < 4; ++m)
            #pragma unroll
            for (int ks = 0; ks < 2; ++ks)
                ar[m][ks] = *reinterpret_cast<const short8*>(&As[Asb + 4096 + m * 1024 + aoffE[ks]]);
        if (U + 2 < nt) STAGE_B(U + 2, 0);
        asm volatile("" ::: "memory");
        __builtin_amdgcn_s_barrier();
        __builtin_amdgcn_s_setprio(1);
        #pragma unroll
        for (int m = 0; m < 4; ++m)
            #pragma unroll
            for (int n = 0; n < 2; ++n)
                #pragma unroll
                for (int ks = 0; ks < 2; ++ks)
                    acc[4 + m][2 + n] = __builtin_amdgcn_mfma_f32_16x16x32_bf16(ar[m][ks], br1[n][ks], acc[4 + m][2 + n], 0, 0, 0);
        __builtin_amdgcn_s_setprio(0);
        asm volatile("" ::: "memory");
        __builtin_amdgcn_s_barrier();

        // ---- P4: stage A(U+2,h0)+B(U+2,h1); MFMA Q10; vmcnt; barrier
        if (U + 2 < nt) { STAGE_A(U + 2, 0); STAGE_B(U + 2, 1); }
        asm volatile("" ::: "memory");
        __builtin_amdgcn_s_barrier();
        __builtin_amdgcn_s_setprio(1);
        #pragma unroll
        for (int m = 0; m < 4; ++m)
            #pragma unroll
            for (int n = 0; n < 2; ++n)
                #pragma unroll
                for (int ks = 0; ks < 2; ++ks)
                    acc[4 + m][n] = __builtin_amdgcn_mfma_f32_16x16x32_bf16(ar[m][ks], br0[n][ks], acc[4 + m][n], 0, 0, 0);
        __builtin_amdgcn_s_setprio(0);
        if (U < nt - 2) {
            asm volatile("s_waitcnt vmcnt(6)" ::: "memory");
        } else if (U == nt - 2) {
            asm volatile("s_waitcnt vmcnt(0)" ::: "memory");
        }
        __builtin_amdgcn_s_barrier();
    }
#undef STAGE_A
#undef STAGE_B

    // epilogue: head-packed bf16 (col -> which/h/d; row -> b,s)
    #pragma unroll
    for (int m = 0; m < 8; ++m) {
        #pragma unroll
        for (int n = 0; n < 4; ++n) {
            const int col = n0 + wc * 64 + n * 16 + lr;
            const int which = col >> 11;
            const int h = (col >> 7) & 15;
            const int d = col & 127;
            #pragma unroll
            for (int r = 0; r < 4; ++r) {
                const int row = m0 + wr * 128 + m * 16 + lg * 4 + r;
                const int bb = row >> 11, s = row & 2047;
                Cout[(long)which * M * 2048 + (((long)(bb * 16 + h)) * 2048 + s) * 128 + d] = f2bf(acc[m][n][r]);
            }
        }
    }
}

// ---------------- GEMM NT 128x128 (proven 2-phase dbuf) — used for wo ----------------
template<int OUT_MODE>
__global__ __launch_bounds__(256) void gemm_nt(const ushort_t* __restrict__ A,
                                               const ushort_t* __restrict__ Bw,
                                               void* __restrict__ Cout,
                                               int M, int N, int K) {
    __shared__ __align__(16) ushort_t As[2 * 128 * 32];
    __shared__ __align__(16) ushort_t Bs[2 * 128 * 32];
    const int t = threadIdx.x;
    const int wid = t >> 6, lane = t & 63;
    const int wm = wid >> 1, wn = wid & 1;
    const int lr = lane & 15, lg = lane >> 4;

    const int ntc = N >> 7;
    const int nwg = (M >> 7) * ntc;
    const int bid = blockIdx.y * gridDim.x + blockIdx.x;
    const int cpx = nwg >> 3;
    const int swz = (bid & 7) * cpx + (bid >> 3);
    const int m0 = (swz / ntc) * 128, n0 = (swz % ntc) * 128;

    f32x4 acc[4][4] = {};

    const int sh0 = wid * 1024 + lane * 8;
    const int sh1 = sh0 + 512;
    const int r0 = sh0 >> 5, c0 = sh0 & 31;
    const int r1 = sh1 >> 5, c1 = sh1 & 31;

    const ushort_t* gA0 = A + (long)(m0 + r0) * K + c0;
    const ushort_t* gA1 = A + (long)(m0 + r1) * K + c1;
    const ushort_t* gB0 = Bw + (long)(n0 + r0) * K + c0;
    const ushort_t* gB1 = Bw + (long)(n0 + r1) * K + c1;

    auto stage = [&](int k0, int nb) {
        ushort_t* as = As + nb * 4096;
        ushort_t* bs = Bs + nb * 4096;
        __builtin_amdgcn_global_load_lds((const __attribute__((address_space(1))) unsigned int*)(gA0 + k0),
                                         (__attribute__((address_space(3))) unsigned int*)(as + sh0), 16, 0, 0);
        __builtin_amdgcn_global_load_lds((const __attribute__((address_space(1))) unsigned int*)(gA1 + k0),
                                         (__attribute__((address_space(3))) unsigned int*)(as + sh1), 16, 0, 0);
        __builtin_amdgcn_global_load_lds((const __attribute__((address_space(1))) unsigned int*)(gB0 + k0),
                                         (__attribute__((address_space(3))) unsigned int*)(bs + sh0), 16, 0, 0);
        __builtin_amdgcn_global_load_lds((const __attribute__((address_space(1))) unsigned int*)(gB1 + k0),
                                         (__attribute__((address_space(3))) unsigned int*)(bs + sh1), 16, 0, 0);
    };

    const int nt = K >> 5;
    stage(0, 0);
    __syncthreads();
    int cur = 0;

    for (int ti = 0; ti < nt; ++ti) {
        if (ti + 1 < nt) stage((ti + 1) << 5, cur ^ 1);
        const ushort_t* as = As + cur * 4096;
        const ushort_t* bs = Bs + cur * 4096;
        short8 af[4], bfr[4];
        #pragma unroll
        for (int m = 0; m < 4; ++m)
            af[m] = *reinterpret_cast<const short8*>(&as[(wm * 64 + m * 16 + lr) * 32 + lg * 8]);
        #pragma unroll
        for (int n = 0; n < 4; ++n)
            bfr[n] = *reinterpret_cast<const short8*>(&bs[(wn * 64 + n * 16 + lr) * 32 + lg * 8]);
        #pragma unroll
        for (int m = 0; m < 4; ++m)
            #pragma unroll
            for (int n = 0; n < 4; ++n)
                acc[m][n] = __builtin_amdgcn_mfma_f32_16x16x32_bf16(af[m], bfr[n], acc[m][n], 0, 0, 0);
        __syncthreads();
        cur ^= 1;
    }

    #pragma unroll
    for (int m = 0; m < 4; ++m) {
        #pragma unroll
        for (int n = 0; n < 4; ++n) {
            const int col = n0 + wn * 64 + n * 16 + lr;
            #pragma unroll
            for (int r = 0; r < 4; ++r) {
                const int row = m0 + wm * 64 + m * 16 + lg * 4 + r;
                float v = acc[m][n][r];
                if (OUT_MODE == 0) {
                    ((float*)Cout)[(long)row * N + col] = v;
                } else {
                    const int which = col >> 11;
                    const int h = (col >> 7) & 15;
                    const int d = col & 127;
                    const int b = row >> 11, s = row & 2047;
                    ((ushort_t*)Cout)[(long)which * M * 2048 +
                                      (((long)(b * 16 + h)) * 2048 + s) * 128 + d] = f2bf(v);
                }
            }
        }
    }
}

// ---------------- RoPE in-place on packed Q|K ([2, B*H, S, 128] contiguous) ----------------
__global__ void rope_kernel(ushort_t* __restrict__ X, const float* __restrict__ fc,
                            const float* __restrict__ fs, int total8) {
    int i = blockIdx.x * blockDim.x + threadIdx.x;
    if (i >= total8) return;
    const int s_idx = (i >> 4) & 2047;
    const int i0 = (i & 15) * 4;
    const long base = (long)i * 8;
    short8 v = *reinterpret_cast<const short8*>(X + base);
    short8 o;
    #pragma unroll
    for (int p = 0; p < 4; ++p) {
        float c  = fc[(long)s_idx * 64 + i0 + p];
        float sn = fs[(long)s_idx * 64 + i0 + p];
        float x0 = bf2f(v[2 * p]), x1 = bf2f(v[2 * p + 1]);
        o[2 * p]     = (short)f2bf(x0 * c - x1 * sn);
        o[2 * p + 1] = (short)f2bf(x0 * sn + x1 * c);
    }
    *reinterpret_cast<short8*>(X + base) = o;
}

// ---------------- V transpose: Vp[B*H, S, 128] -> Vt[B*H, 128, S] ----------------
__global__ void vtrans_kernel(const ushort_t* __restrict__ Vp, ushort_t* __restrict__ Vt,
                              int S) {
    const int bh = blockIdx.y;
    const int s0 = blockIdx.x * 16 + ((threadIdx.x >> 7) * 8);
    const int d = threadIdx.x & 127;
    const ushort_t* src = Vp + (long)bh * S * 128;
    short8 o;
    #pragma unroll
    for (int i = 0; i < 8; ++i)
        o[i] = (short)src[(long)(s0 + i) * 128 + d];
    *reinterpret_cast<short8*>(Vt + ((long)bh * 128 + d) * S + s0) = o;
}

// ---------------- causal flash attention (folded, T14 async-STAGE K/V) ----------------
__global__ __launch_bounds__(256, 3) void attn_kernel(const ushort_t* __restrict__ Qp,
                                                      const ushort_t* __restrict__ Kp,
                                                      const ushort_t* __restrict__ Vtg,
                                                      ushort_t* __restrict__ O,
                                                      int S, int H) {
    __shared__ __align__(16) ushort_t Ks[64][136];
    __shared__ __align__(16) ushort_t Vs[128][72];
    __shared__ __align__(16) ushort_t Pl[4][16][72];
    const int t = threadIdx.x, wid = t >> 6, lane = t & 63;
    const int lr = lane & 15, lg = lane >> 4;
    const int bh = blockIdx.y;
    const int b = bh / H, h = bh % H;
    const ushort_t* Qh = Qp + (long)bh * S * 128;
    const ushort_t* Kh = Kp + (long)bh * S * 128;
    const ushort_t* Vth = Vtg + (long)bh * 128 * S;
    const int nq = S / 64;
    const float scale = 0.08838834764831845f;

    const int ksr = t >> 2;
    const int ksc = (t & 3) * 32;
    const int vsr = t & 127;
    const int vsc = (t >> 7) * 32;

    for (int qsel = 0; qsel < 2; ++qsel) {
        const int qt = qsel ? (nq - 1 - blockIdx.x) : blockIdx.x;
        const int qb0 = qt * 64;

        const int qrow = qb0 + wid * 16 + lr;
        short8 qf[4];
        #pragma unroll
        for (int kk = 0; kk < 4; ++kk)
            qf[kk] = *reinterpret_cast<const short8*>(Qh + (long)qrow * 128 + kk * 32 + lg * 8);

        f32x4 oacc[8] = {};
        float mrow[4], lsum[4];
        #pragma unroll
        for (int r = 0; r < 4; ++r) { mrow[r] = -INFINITY; lsum[r] = 0.f; }

        const int nkt = qt + 1;

        short8 kreg[4], vreg[4];
        {
            const ushort_t* kgp = Kh + t * 32;
            const ushort_t* vgp = Vth + (long)vsr * S + vsc;
            #pragma unroll
            for (int j = 0; j < 4; ++j) kreg[j] = *reinterpret_cast<const short8*>(kgp + j * 8);
            #pragma unroll
            for (int j = 0; j < 4; ++j) vreg[j] = *reinterpret_cast<const short8*>(vgp + j * 8);
        }

        for (int kt = 0; kt < nkt; ++kt) {
            const int kv0 = kt * 64;
            __syncthreads();
            #pragma unroll
            for (int j = 0; j < 4; ++j)
                *reinterpret_cast<short8*>(&Ks[ksr][ksc + j * 8]) = kreg[j];
            #pragma unroll
            for (int j = 0; j < 4; ++j)
                *reinterpret_cast<short8*>(&Vs[vsr][vsc + j * 8]) = vreg[j];
            __syncthreads();
            if (kt + 1 < nkt) {
                const ushort_t* kgp = Kh + (long)(kv0 + 64) * 128 + t * 32;
                const ushort_t* vgp = Vth + (long)vsr * S + kv0 + 64 + vsc;
                #pragma unroll
                for (int j = 0; j < 4; ++j) kreg[j] = *reinterpret_cast<const short8*>(kgp + j * 8);
                #pragma unroll
                for (int j = 0; j < 4; ++j) vreg[j] = *reinterpret_cast<const short8*>(vgp + j * 8);
            }

            f32x4 sacc[4] = {};
            #pragma unroll
            for (int kk = 0; kk < 4; ++kk) {
                #pragma unroll
                for (int n = 0; n < 4; ++n) {
                    short8 kf = *reinterpret_cast<const short8*>(&Ks[n * 16 + lr][kk * 32 + lg * 8]);
                    sacc[n] = __builtin_amdgcn_mfma_f32_16x16x32_bf16(qf[kk], kf, sacc[n], 0, 0, 0);
                }
            }
            float sv[4][4];
            const int myq = qb0 + wid * 16 + lg * 4;
            #pragma unroll
            for (int n = 0; n < 4; ++n) {
                int kcol = kv0 + n * 16 + lr;
                #pragma unroll
                for (int r = 0; r < 4; ++r) {
                    float xv = sacc[n][r] * scale;
                    sv[n][r] = (kcol > myq + r) ? -1e9f : xv;
                }
            }
            float alpha[4];
            #pragma unroll
            for (int r = 0; r < 4; ++r) {
                float mx = fmaxf(fmaxf(sv[0][r], sv[1][r]), fmaxf(sv[2][r], sv[3][r]));
                #pragma unroll
                for (int off = 1; off < 16; off <<= 1)
                    mx = fmaxf(mx, __shfl_xor(mx, off));
                float mnew = fmaxf(mrow[r], mx);
                alpha[r] = __expf(mrow[r] - mnew);
                float ts = 0.f;
                #pragma unroll
                for (int n = 0; n < 4; ++n) {
                    float p = __expf(sv[n][r] - mnew);
                    sv[n][r] = p;
                    ts += p;
                }
                #pragma unroll
                for (int off = 1; off < 16; off <<= 1)
                    ts += __shfl_xor(ts, off);
                lsum[r] = lsum[r] * alpha[r] + ts;
                mrow[r] = mnew;
            }
            #pragma unroll
            for (int f = 0; f < 8; ++f)
                #pragma unroll
                for (int r = 0; r < 4; ++r)
                    oacc[f][r] *= alpha[r];
            #pragma unroll
            for (int n = 0; n < 4; ++n)
                #pragma unroll
                for (int r = 0; r < 4; ++r)
                    Pl[wid][lg * 4 + r][n * 16 + lr] = f2bf(sv[n][r]);
            __asm volatile("" ::: "memory");
            short8 pf[2];
            #pragma unroll
            for (int ks = 0; ks < 2; ++ks)
                pf[ks] = *reinterpret_cast<const short8*>(&Pl[wid][lr][ks * 32 + lg * 8]);
            #pragma unroll
            for (int f = 0; f < 8; ++f) {
                #pragma unroll
                for (int ks = 0; ks < 2; ++ks) {
                    short8 vf = *reinterpret_cast<const short8*>(&Vs[f * 16 + lr][ks * 32 + lg * 8]);
                    oacc[f] = __builtin_amdgcn_mfma_f32_16x16x32_bf16(pf[ks], vf, oacc[f], 0, 0, 0);
                }
            }
        }
        float inv[4];
        #pragma unroll
        for (int r = 0; r < 4; ++r) inv[r] = 1.f / lsum[r];
        ushort_t* Oh = O + (long)b * S * 2048 + h * 128;
        #pragma unroll
        for (int f = 0; f < 8; ++f) {
            #pragma unroll
            for (int r = 0; r < 4; ++r) {
                int row = qb0 + wid * 16 + lg * 4 + r;
                int col = f * 16 + lr;
                Oh[(long)row * 2048 + col] = f2bf(oacc[f][r] * inv[r]);
            }
        }
    }
}

extern "C" void kernel_launch(void* const* d_in, const int* in_sizes, int n_in,
                              void* d_out, int out_size, void* d_ws, size_t ws_size,
                              hipStream_t stream) {
    const float* x  = (const float*)d_in[0];
    const float* fc = (const float*)d_in[1];
    const float* fs = (const float*)d_in[2];
    const float* wq = (const float*)d_in[3];
    const float* wk = (const float*)d_in[4];
    const float* wv = (const float*)d_in[5];
    const float* wo = (const float*)d_in[6];
    float* out = (float*)d_out;

    const int B = 2, S = 2048, D = 2048, H = 16;
    const int M = B * S;            // 4096
    const size_t MD = (size_t)M * D;
    const size_t DD = (size_t)D * D;

    char* ws = (char*)d_ws;
    ushort_t* xbf = (ushort_t*)ws;
    ushort_t* wqb = (ushort_t*)(ws + MD * 2);
    ushort_t* wob = wqb + 3 * DD;
    ushort_t* qp  = wqb + 4 * DD;
    ushort_t* kp  = qp + MD;
    ushort_t* vp  = kp + MD;
    ushort_t* vtg   = xbf;           // overlay: x dead after QKV GEMM
    ushort_t* attnb = vp;            // overlay: Vp dead after vtrans

    cvt_kernel<<<2048, 256, 0, stream>>>(x, xbf, (int)(MD / 8));
    cvtw_kernel<<<2048, 256, 0, stream>>>(wq, wk, wv, wo, wqb, (int)(DD / 8));

    // fused QKV projection: 256^2 8-phase kernel, head-packed epilogue
    dim3 gq(6144 / 256, M / 256);
    gemm256_qkv<<<gq, 512, 131072, stream>>>(xbf, wqb, qp, M, 3 * D, D);

    const int total8 = (int)(2 * MD / 8);
    rope_kernel<<<(total8 + 255) / 256, 256, 0, stream>>>(qp, fc, fs, total8);

    dim3 gv(S / 16, B * H);
    vtrans_kernel<<<gv, 256, 0, stream>>>(vp, vtg, S);
    dim3 ga(S / 128, B * H);
    attn_kernel<<<ga, 256, 0, stream>>>(qp, kp, vtg, attnb, S, H);

    dim3 gg(D / 128, M / 128);
    gemm_nt<0><<<gg, 256, 0, stream>>>(attnb, wob, out, M, D, D);
}

// Round 7
// 322.851 us; speedup vs baseline: 1.0001x; 1.0001x over previous
//
#include <hip/hip_runtime.h>
#include <hip/hip_bf16.h>
#include <math.h>

typedef __attribute__((ext_vector_type(8))) short short8;
typedef __attribute__((ext_vector_type(4))) float f32x4;
typedef unsigned short ushort_t;

__device__ __forceinline__ ushort_t f2bf(float f) {
    union { float f; unsigned u; } v; v.f = f;
    unsigned r = v.u + 0x7FFF + ((v.u >> 16) & 1);
    return (ushort_t)(r >> 16);
}
__device__ __forceinline__ float bf2f(short s) {
    union { unsigned u; float f; } v; v.u = ((unsigned)(ushort_t)s) << 16;
    return v.f;
}

// ---------------- fp32 -> bf16 convert (x) ----------------
__global__ void cvt_kernel(const float* __restrict__ src, ushort_t* __restrict__ dst, int n8) {
    int i = blockIdx.x * blockDim.x + threadIdx.x;
    int stride = gridDim.x * blockDim.x;
    for (; i < n8; i += stride) {
        const float4* s = reinterpret_cast<const float4*>(src) + (size_t)i * 2;
        float4 a = s[0], b = s[1];
        short8 o;
        o[0] = (short)f2bf(a.x); o[1] = (short)f2bf(a.y);
        o[2] = (short)f2bf(a.z); o[3] = (short)f2bf(a.w);
        o[4] = (short)f2bf(b.x); o[5] = (short)f2bf(b.y);
        o[6] = (short)f2bf(b.z); o[7] = (short)f2bf(b.w);
        reinterpret_cast<short8*>(dst)[i] = o;
    }
}

// ---------------- fused weight convert: wq|wk|wv|wo -> contiguous bf16 ----------------
__global__ void cvtw_kernel(const float* __restrict__ w0, const float* __restrict__ w1,
                            const float* __restrict__ w2, const float* __restrict__ w3,
                            ushort_t* __restrict__ dst, int dd8) {
    int i = blockIdx.x * blockDim.x + threadIdx.x;
    int stride = gridDim.x * blockDim.x;
    const int total = dd8 * 4;
    for (; i < total; i += stride) {
        int which = i / dd8;
        int off = i - which * dd8;
        const float* src = (which == 0) ? w0 : (which == 1) ? w1 : (which == 2) ? w2 : w3;
        const float4* s = reinterpret_cast<const float4*>(src) + (size_t)off * 2;
        float4 a = s[0], b = s[1];
        short8 o;
        o[0] = (short)f2bf(a.x); o[1] = (short)f2bf(a.y);
        o[2] = (short)f2bf(a.z); o[3] = (short)f2bf(a.w);
        o[4] = (short)f2bf(b.x); o[5] = (short)f2bf(b.y);
        o[6] = (short)f2bf(b.z); o[7] = (short)f2bf(b.w);
        reinterpret_cast<short8*>(dst)[i] = o;
    }
}

// ============ 256x256 8-phase GEMM (QKV): BK=64, 8 waves, counted-vmcnt pipeline ============
// Same schedule as round 6 (swizzle verified: 0 bank conflicts) with three fixes:
//  - ks-OUTER MFMA order: dependent acc-pair MFMAs spaced by 8 independents (was back-to-back)
//  - K-loop unrolled x2: compile-time LDS buffer parity (m201's 2-K-tiles/iter)
//  - explicit lgkmcnt(0)+sched_barrier(0) after each mid-barrier (template form)
__global__ __launch_bounds__(512, 2) void gemm256_qkv(const ushort_t* __restrict__ A,
                                                      const ushort_t* __restrict__ Bw,
                                                      ushort_t* __restrict__ Cout,
                                                      int M, int N, int K) {
    extern __shared__ __align__(16) ushort_t lds[];
    ushort_t* As = lds;              // 32768 elems
    ushort_t* Bs = lds + 32768;
    const int t = threadIdx.x;
    const int wid = t >> 6, lane = t & 63;
    const int wr = wid >> 2, wc = wid & 3;
    const int lr = lane & 15, lg = lane >> 4;

    const int ntc = N >> 8;
    const int nwg = (M >> 8) * ntc;
    const int bid = blockIdx.y * gridDim.x + blockIdx.x;
    const int cpx = nwg >> 3;
    const int swz = (bid & 7) * cpx + (bid >> 3);
    const int m0 = (swz / ntc) * 256, n0 = (swz % ntc) * 256;

    f32x4 acc[8][4] = {};

    const int r0 = t >> 3;
    const int c0 = (t & 7) ^ (r0 & 7);
    const ushort_t* gA = A + (long)(m0 + r0) * K + c0 * 8;
    const ushort_t* gB = Bw + (long)(n0 + r0) * K + c0 * 8;

    int aoffE[2];
    aoffE[0] = lr * 64 + (((0 + lg) ^ (lr & 7)) << 3);
    aoffE[1] = lr * 64 + (((4 + lg) ^ (lr & 7)) << 3);

    const int nt = K >> 6;   // 32 (even)

#define STAGE_A(X, h) do { const int p_ = (X) & 1;                                             \
    __builtin_amdgcn_global_load_lds((const __attribute__((address_space(1))) unsigned int*)   \
        (gA + (long)((h) * 128) * K + (X) * 64),                                               \
        (__attribute__((address_space(3))) unsigned int*)(As + (p_ * 2 + (h)) * 8192 + t * 8), \
        16, 0, 0);                                                                             \
    __builtin_amdgcn_global_load_lds((const __attribute__((address_space(1))) unsigned int*)   \
        (gA + (long)((h) * 128 + 64) * K + (X) * 64),                                          \
        (__attribute__((address_space(3))) unsigned int*)(As + (p_ * 2 + (h)) * 8192 + 4096 + t * 8), \
        16, 0, 0); } while (0)

#define STAGE_B(X, h) do { const int p_ = (X) & 1;                                             \
    __builtin_amdgcn_global_load_lds((const __attribute__((address_space(1))) unsigned int*)   \
        (gB + (long)((h) * 128) * K + (X) * 64),                                               \
        (__attribute__((address_space(3))) unsigned int*)(Bs + (p_ * 2 + (h)) * 8192 + t * 8), \
        16, 0, 0);                                                                             \
    __builtin_amdgcn_global_load_lds((const __attribute__((address_space(1))) unsigned int*)   \
        (gB + (long)((h) * 128 + 64) * K + (X) * 64),                                          \
        (__attribute__((address_space(3))) unsigned int*)(Bs + (p_ * 2 + (h)) * 8192 + 4096 + t * 8), \
        16, 0, 0); } while (0)

#define MIDSYNC() do {                                             \
    asm volatile("" ::: "memory");                                 \
    __builtin_amdgcn_s_barrier();                                  \
    asm volatile("s_waitcnt lgkmcnt(0)" ::: "memory");             \
    __builtin_amdgcn_sched_barrier(0); } while (0)

#define ENDBAR() do {                                              \
    asm volatile("" ::: "memory");                                 \
    __builtin_amdgcn_s_barrier(); } while (0)

// MFMA quadrant: ks-outer => 8 independent MFMAs between dependent acc pairs
#define MFMA_Q(AROW, BCOL, AR, BR) do {                            \
    __builtin_amdgcn_s_setprio(1);                                 \
    _Pragma("unroll")                                              \
    for (int ks = 0; ks < 2; ++ks)                                 \
        _Pragma("unroll")                                          \
        for (int m = 0; m < 4; ++m)                                \
            _Pragma("unroll")                                      \
            for (int n = 0; n < 2; ++n)                            \
                acc[(AROW) + m][(BCOL) + n] =                      \
                    __builtin_amdgcn_mfma_f32_16x16x32_bf16((AR)[m][ks], (BR)[n][ks], acc[(AROW) + m][(BCOL) + n], 0, 0, 0); \
    __builtin_amdgcn_s_setprio(0); } while (0)

#define KTILE(U, BUF) do {                                                                     \
    const int Asb = ((BUF) * 2 + wr) * 8192;                                                   \
    const int Bcb = ((BUF) * 2 + (wc >> 1)) * 8192 + (wc & 1) * 4096;                          \
    /* P1: read A-h0 + B-n0; stage A(U+1,h1); MFMA Q00 */                                      \
    _Pragma("unroll")                                                                          \
    for (int m = 0; m < 4; ++m)                                                                \
        _Pragma("unroll")                                                                      \
        for (int ks = 0; ks < 2; ++ks)                                                         \
            ar[m][ks] = *reinterpret_cast<const short8*>(&As[Asb + m * 1024 + aoffE[ks]]);     \
    _Pragma("unroll")                                                                          \
    for (int n = 0; n < 2; ++n)                                                                \
        _Pragma("unroll")                                                                      \
        for (int ks = 0; ks < 2; ++ks)                                                         \
            br0[n][ks] = *reinterpret_cast<const short8*>(&Bs[Bcb + n * 1024 + aoffE[ks]]);    \
    if ((U) + 1 < nt) STAGE_A((U) + 1, 1);                                                     \
    MIDSYNC();                                                                                 \
    MFMA_Q(0, 0, ar, br0);                                                                     \
    ENDBAR();                                                                                  \
    /* P2: read B-n1; MFMA Q01 */                                                              \
    _Pragma("unroll")                                                                          \
    for (int n = 0; n < 2; ++n)                                                                \
        _Pragma("unroll")                                                                      \
        for (int ks = 0; ks < 2; ++ks)                                                         \
            br1[n][ks] = *reinterpret_cast<const short8*>(&Bs[Bcb + 2048 + n * 1024 + aoffE[ks]]); \
    MIDSYNC();                                                                                 \
    MFMA_Q(0, 2, ar, br1);                                                                     \
    ENDBAR();                                                                                  \
    /* P3: read A-h1; stage B(U+2,h0); MFMA Q11 */                                             \
    _Pragma("unroll")                                                                          \
    for (int m = 0; m < 4; ++m)                                                                \
        _Pragma("unroll")                                                                      \
        for (int ks = 0; ks < 2; ++ks)                                                         \
            ar[m][ks] = *reinterpret_cast<const short8*>(&As[Asb + 4096 + m * 1024 + aoffE[ks]]); \
    if ((U) + 2 < nt) STAGE_B((U) + 2, 0);                                                     \
    MIDSYNC();                                                                                 \
    MFMA_Q(4, 2, ar, br1);                                                                     \
    ENDBAR();                                                                                  \
    /* P4: stage A(U+2,h0)+B(U+2,h1); MFMA Q10; vmcnt; barrier */                              \
    if ((U) + 2 < nt) { STAGE_A((U) + 2, 0); STAGE_B((U) + 2, 1); }                            \
    asm volatile("" ::: "memory");                                                             \
    __builtin_amdgcn_s_barrier();                                                              \
    MFMA_Q(4, 0, ar, br0);                                                                     \
    if ((U) < nt - 2) {                                                                        \
        asm volatile("s_waitcnt vmcnt(6)" ::: "memory");                                       \
    } else if ((U) == nt - 2) {                                                                \
        asm volatile("s_waitcnt vmcnt(0)" ::: "memory");                                       \
    }                                                                                          \
    __builtin_amdgcn_s_barrier(); } while (0)

    // prologue: tile0 fully (8 loads) then 3 halves of tile1 (6 loads); wait tile0
    STAGE_A(0, 0); STAGE_A(0, 1); STAGE_B(0, 0); STAGE_B(0, 1);
    STAGE_A(1, 0); STAGE_B(1, 0); STAGE_B(1, 1);
    asm volatile("s_waitcnt vmcnt(6)" ::: "memory");
    __builtin_amdgcn_s_barrier();

    short8 ar[4][2], br0[2][2], br1[2][2];

    for (int U = 0; U < nt; U += 2) {
        KTILE(U, 0);
        KTILE(U + 1, 1);
    }
#undef KTILE
#undef MFMA_Q
#undef ENDBAR
#undef MIDSYNC
#undef STAGE_A
#undef STAGE_B

    // epilogue: head-packed bf16 (col -> which/h/d; row -> b,s)
    #pragma unroll
    for (int m = 0; m < 8; ++m) {
        #pragma unroll
        for (int n = 0; n < 4; ++n) {
            const int col = n0 + wc * 64 + n * 16 + lr;
            const int which = col >> 11;
            const int h = (col >> 7) & 15;
            const int d = col & 127;
            #pragma unroll
            for (int r = 0; r < 4; ++r) {
                const int row = m0 + wr * 128 + m * 16 + lg * 4 + r;
                const int bb = row >> 11, s = row & 2047;
                Cout[(long)which * M * 2048 + (((long)(bb * 16 + h)) * 2048 + s) * 128 + d] = f2bf(acc[m][n][r]);
            }
        }
    }
}

// ---------------- GEMM NT 128x128 (proven 2-phase dbuf) — used for wo ----------------
template<int OUT_MODE>
__global__ __launch_bounds__(256) void gemm_nt(const ushort_t* __restrict__ A,
                                               const ushort_t* __restrict__ Bw,
                                               void* __restrict__ Cout,
                                               int M, int N, int K) {
    __shared__ __align__(16) ushort_t As[2 * 128 * 32];
    __shared__ __align__(16) ushort_t Bs[2 * 128 * 32];
    const int t = threadIdx.x;
    const int wid = t >> 6, lane = t & 63;
    const int wm = wid >> 1, wn = wid & 1;
    const int lr = lane & 15, lg = lane >> 4;

    const int ntc = N >> 7;
    const int nwg = (M >> 7) * ntc;
    const int bid = blockIdx.y * gridDim.x + blockIdx.x;
    const int cpx = nwg >> 3;
    const int swz = (bid & 7) * cpx + (bid >> 3);
    const int m0 = (swz / ntc) * 128, n0 = (swz % ntc) * 128;

    f32x4 acc[4][4] = {};

    const int sh0 = wid * 1024 + lane * 8;
    const int sh1 = sh0 + 512;
    const int r0 = sh0 >> 5, c0 = sh0 & 31;
    const int r1 = sh1 >> 5, c1 = sh1 & 31;

    const ushort_t* gA0 = A + (long)(m0 + r0) * K + c0;
    const ushort_t* gA1 = A + (long)(m0 + r1) * K + c1;
    const ushort_t* gB0 = Bw + (long)(n0 + r0) * K + c0;
    const ushort_t* gB1 = Bw + (long)(n0 + r1) * K + c1;

    auto stage = [&](int k0, int nb) {
        ushort_t* as = As + nb * 4096;
        ushort_t* bs = Bs + nb * 4096;
        __builtin_amdgcn_global_load_lds((const __attribute__((address_space(1))) unsigned int*)(gA0 + k0),
                                         (__attribute__((address_space(3))) unsigned int*)(as + sh0), 16, 0, 0);
        __builtin_amdgcn_global_load_lds((const __attribute__((address_space(1))) unsigned int*)(gA1 + k0),
                                         (__attribute__((address_space(3))) unsigned int*)(as + sh1), 16, 0, 0);
        __builtin_amdgcn_global_load_lds((const __attribute__((address_space(1))) unsigned int*)(gB0 + k0),
                                         (__attribute__((address_space(3))) unsigned int*)(bs + sh0), 16, 0, 0);
        __builtin_amdgcn_global_load_lds((const __attribute__((address_space(1))) unsigned int*)(gB1 + k0),
                                         (__attribute__((address_space(3))) unsigned int*)(bs + sh1), 16, 0, 0);
    };

    const int nt = K >> 5;
    stage(0, 0);
    __syncthreads();
    int cur = 0;

    for (int ti = 0; ti < nt; ++ti) {
        if (ti + 1 < nt) stage((ti + 1) << 5, cur ^ 1);
        const ushort_t* as = As + cur * 4096;
        const ushort_t* bs = Bs + cur * 4096;
        short8 af[4], bfr[4];
        #pragma unroll
        for (int m = 0; m < 4; ++m)
            af[m] = *reinterpret_cast<const short8*>(&as[(wm * 64 + m * 16 + lr) * 32 + lg * 8]);
        #pragma unroll
        for (int n = 0; n < 4; ++n)
            bfr[n] = *reinterpret_cast<const short8*>(&bs[(wn * 64 + n * 16 + lr) * 32 + lg * 8]);
        #pragma unroll
        for (int m = 0; m < 4; ++m)
            #pragma unroll
            for (int n = 0; n < 4; ++n)
                acc[m][n] = __builtin_amdgcn_mfma_f32_16x16x32_bf16(af[m], bfr[n], acc[m][n], 0, 0, 0);
        __syncthreads();
        cur ^= 1;
    }

    #pragma unroll
    for (int m = 0; m < 4; ++m) {
        #pragma unroll
        for (int n = 0; n < 4; ++n) {
            const int col = n0 + wn * 64 + n * 16 + lr;
            #pragma unroll
            for (int r = 0; r < 4; ++r) {
                const int row = m0 + wm * 64 + m * 16 + lg * 4 + r;
                float v = acc[m][n][r];
                if (OUT_MODE == 0) {
                    ((float*)Cout)[(long)row * N + col] = v;
                } else {
                    const int which = col >> 11;
                    const int h = (col >> 7) & 15;
                    const int d = col & 127;
                    const int b = row >> 11, s = row & 2047;
                    ((ushort_t*)Cout)[(long)which * M * 2048 +
                                      (((long)(b * 16 + h)) * 2048 + s) * 128 + d] = f2bf(v);
                }
            }
        }
    }
}

// ---------------- RoPE in-place on packed Q|K ([2, B*H, S, 128] contiguous) ----------------
__global__ void rope_kernel(ushort_t* __restrict__ X, const float* __restrict__ fc,
                            const float* __restrict__ fs, int total8) {
    int i = blockIdx.x * blockDim.x + threadIdx.x;
    if (i >= total8) return;
    const int s_idx = (i >> 4) & 2047;
    const int i0 = (i & 15) * 4;
    const long base = (long)i * 8;
    short8 v = *reinterpret_cast<const short8*>(X + base);
    short8 o;
    #pragma unroll
    for (int p = 0; p < 4; ++p) {
        float c  = fc[(long)s_idx * 64 + i0 + p];
        float sn = fs[(long)s_idx * 64 + i0 + p];
        float x0 = bf2f(v[2 * p]), x1 = bf2f(v[2 * p + 1]);
        o[2 * p]     = (short)f2bf(x0 * c - x1 * sn);
        o[2 * p + 1] = (short)f2bf(x0 * sn + x1 * c);
    }
    *reinterpret_cast<short8*>(X + base) = o;
}

// ---------------- V transpose: Vp[B*H, S, 128] -> Vt[B*H, 128, S] ----------------
__global__ void vtrans_kernel(const ushort_t* __restrict__ Vp, ushort_t* __restrict__ Vt,
                              int S) {
    const int bh = blockIdx.y;
    const int s0 = blockIdx.x * 16 + ((threadIdx.x >> 7) * 8);
    const int d = threadIdx.x & 127;
    const ushort_t* src = Vp + (long)bh * S * 128;
    short8 o;
    #pragma unroll
    for (int i = 0; i < 8; ++i)
        o[i] = (short)src[(long)(s0 + i) * 128 + d];
    *reinterpret_cast<short8*>(Vt + ((long)bh * 128 + d) * S + s0) = o;
}

// ---------------- causal flash attention (folded, T14 async-STAGE K/V) ----------------
__global__ __launch_bounds__(256, 3) void attn_kernel(const ushort_t* __restrict__ Qp,
                                                      const ushort_t* __restrict__ Kp,
                                                      const ushort_t* __restrict__ Vtg,
                                                      ushort_t* __restrict__ O,
                                                      int S, int H) {
    __shared__ __align__(16) ushort_t Ks[64][136];
    __shared__ __align__(16) ushort_t Vs[128][72];
    __shared__ __align__(16) ushort_t Pl[4][16][72];
    const int t = threadIdx.x, wid = t >> 6, lane = t & 63;
    const int lr = lane & 15, lg = lane >> 4;
    const int bh = blockIdx.y;
    const int b = bh / H, h = bh % H;
    const ushort_t* Qh = Qp + (long)bh * S * 128;
    const ushort_t* Kh = Kp + (long)bh * S * 128;
    const ushort_t* Vth = Vtg + (long)bh * 128 * S;
    const int nq = S / 64;
    const float scale = 0.08838834764831845f;

    const int ksr = t >> 2;
    const int ksc = (t & 3) * 32;
    const int vsr = t & 127;
    const int vsc = (t >> 7) * 32;

    for (int qsel = 0; qsel < 2; ++qsel) {
        const int qt = qsel ? (nq - 1 - blockIdx.x) : blockIdx.x;
        const int qb0 = qt * 64;

        const int qrow = qb0 + wid * 16 + lr;
        short8 qf[4];
        #pragma unroll
        for (int kk = 0; kk < 4; ++kk)
            qf[kk] = *reinterpret_cast<const short8*>(Qh + (long)qrow * 128 + kk * 32 + lg * 8);

        f32x4 oacc[8] = {};
        float mrow[4], lsum[4];
        #pragma unroll
        for (int r = 0; r < 4; ++r) { mrow[r] = -INFINITY; lsum[r] = 0.f; }

        const int nkt = qt + 1;

        short8 kreg[4], vreg[4];
        {
            const ushort_t* kgp = Kh + t * 32;
            const ushort_t* vgp = Vth + (long)vsr * S + vsc;
            #pragma unroll
            for (int j = 0; j < 4; ++j) kreg[j] = *reinterpret_cast<const short8*>(kgp + j * 8);
            #pragma unroll
            for (int j = 0; j < 4; ++j) vreg[j] = *reinterpret_cast<const short8*>(vgp + j * 8);
        }

        for (int kt = 0; kt < nkt; ++kt) {
            const int kv0 = kt * 64;
            __syncthreads();
            #pragma unroll
            for (int j = 0; j < 4; ++j)
                *reinterpret_cast<short8*>(&Ks[ksr][ksc + j * 8]) = kreg[j];
            #pragma unroll
            for (int j = 0; j < 4; ++j)
                *reinterpret_cast<short8*>(&Vs[vsr][vsc + j * 8]) = vreg[j];
            __syncthreads();
            if (kt + 1 < nkt) {
                const ushort_t* kgp = Kh + (long)(kv0 + 64) * 128 + t * 32;
                const ushort_t* vgp = Vth + (long)vsr * S + kv0 + 64 + vsc;
                #pragma unroll
                for (int j = 0; j < 4; ++j) kreg[j] = *reinterpret_cast<const short8*>(kgp + j * 8);
                #pragma unroll
                for (int j = 0; j < 4; ++j) vreg[j] = *reinterpret_cast<const short8*>(vgp + j * 8);
            }

            f32x4 sacc[4] = {};
            #pragma unroll
            for (int kk = 0; kk < 4; ++kk) {
                #pragma unroll
                for (int n = 0; n < 4; ++n) {
                    short8 kf = *reinterpret_cast<const short8*>(&Ks[n * 16 + lr][kk * 32 + lg * 8]);
                    sacc[n] = __builtin_amdgcn_mfma_f32_16x16x32_bf16(qf[kk], kf, sacc[n], 0, 0, 0);
                }
            }
            float sv[4][4];
            const int myq = qb0 + wid * 16 + lg * 4;
            #pragma unroll
            for (int n = 0; n < 4; ++n) {
                int kcol = kv0 + n * 16 + lr;
                #pragma unroll
                for (int r = 0; r < 4; ++r) {
                    float xv = sacc[n][r] * scale;
                    sv[n][r] = (kcol > myq + r) ? -1e9f : xv;
                }
            }
            float alpha[4];
            #pragma unroll
            for (int r = 0; r < 4; ++r) {
                float mx = fmaxf(fmaxf(sv[0][r], sv[1][r]), fmaxf(sv[2][r], sv[3][r]));
                #pragma unroll
                for (int off = 1; off < 16; off <<= 1)
                    mx = fmaxf(mx, __shfl_xor(mx, off));
                float mnew = fmaxf(mrow[r], mx);
                alpha[r] = __expf(mrow[r] - mnew);
                float ts = 0.f;
                #pragma unroll
                for (int n = 0; n < 4; ++n) {
                    float p = __expf(sv[n][r] - mnew);
                    sv[n][r] = p;
                    ts += p;
                }
                #pragma unroll
                for (int off = 1; off < 16; off <<= 1)
                    ts += __shfl_xor(ts, off);
                lsum[r] = lsum[r] * alpha[r] + ts;
                mrow[r] = mnew;
            }
            #pragma unroll
            for (int f = 0; f < 8; ++f)
                #pragma unroll
                for (int r = 0; r < 4; ++r)
                    oacc[f][r] *= alpha[r];
            #pragma unroll
            for (int n = 0; n < 4; ++n)
                #pragma unroll
                for (int r = 0; r < 4; ++r)
                    Pl[wid][lg * 4 + r][n * 16 + lr] = f2bf(sv[n][r]);
            __asm volatile("" ::: "memory");
            short8 pf[2];
            #pragma unroll
            for (int ks = 0; ks < 2; ++ks)
                pf[ks] = *reinterpret_cast<const short8*>(&Pl[wid][lr][ks * 32 + lg * 8]);
            // PV: ks-outer => dependent oacc[f] pairs spaced by 8 independent MFMAs
            #pragma unroll
            for (int ks = 0; ks < 2; ++ks) {
                #pragma unroll
                for (int f = 0; f < 8; ++f) {
                    short8 vf = *reinterpret_cast<const short8*>(&Vs[f * 16 + lr][ks * 32 + lg * 8]);
                    oacc[f] = __builtin_amdgcn_mfma_f32_16x16x32_bf16(pf[ks], vf, oacc[f], 0, 0, 0);
                }
            }
        }
        float inv[4];
        #pragma unroll
        for (int r = 0; r < 4; ++r) inv[r] = 1.f / lsum[r];
        ushort_t* Oh = O + (long)b * S * 2048 + h * 128;
        #pragma unroll
        for (int f = 0; f < 8; ++f) {
            #pragma unroll
            for (int r = 0; r < 4; ++r) {
                int row = qb0 + wid * 16 + lg * 4 + r;
                int col = f * 16 + lr;
                Oh[(long)row * 2048 + col] = f2bf(oacc[f][r] * inv[r]);
            }
        }
    }
}

extern "C" void kernel_launch(void* const* d_in, const int* in_sizes, int n_in,
                              void* d_out, int out_size, void* d_ws, size_t ws_size,
                              hipStream_t stream) {
    const float* x  = (const float*)d_in[0];
    const float* fc = (const float*)d_in[1];
    const float* fs = (const float*)d_in[2];
    const float* wq = (const float*)d_in[3];
    const float* wk = (const float*)d_in[4];
    const float* wv = (const float*)d_in[5];
    const float* wo = (const float*)d_in[6];
    float* out = (float*)d_out;

    const int B = 2, S = 2048, D = 2048, H = 16;
    const int M = B * S;            // 4096
    const size_t MD = (size_t)M * D;
    const size_t DD = (size_t)D * D;

    char* ws = (char*)d_ws;
    ushort_t* xbf = (ushort_t*)ws;
    ushort_t* wqb = (ushort_t*)(ws + MD * 2);
    ushort_t* wob = wqb + 3 * DD;
    ushort_t* qp  = wqb + 4 * DD;
    ushort_t* kp  = qp + MD;
    ushort_t* vp  = kp + MD;
    ushort_t* vtg   = xbf;           // overlay: x dead after QKV GEMM
    ushort_t* attnb = vp;            // overlay: Vp dead after vtrans

    cvt_kernel<<<2048, 256, 0, stream>>>(x, xbf, (int)(MD / 8));
    cvtw_kernel<<<2048, 256, 0, stream>>>(wq, wk, wv, wo, wqb, (int)(DD / 8));

    dim3 gq(6144 / 256, M / 256);
    gemm256_qkv<<<gq, 512, 131072, stream>>>(xbf, wqb, qp, M, 3 * D, D);

    const int total8 = (int)(2 * MD / 8);
    rope_kernel<<<(total8 + 255) / 256, 256, 0, stream>>>(qp, fc, fs, total8);

    dim3 gv(S / 16, B * H);
    vtrans_kernel<<<gv, 256, 0, stream>>>(vp, vtg, S);
    dim3 ga(S / 128, B * H);
    attn_kernel<<<ga, 256, 0, stream>>>(qp, kp, vtg, attnb, S, H);

    dim3 gg(D / 128, M / 128);
    gemm_nt<0><<<gg, 256, 0, stream>>>(attnb, wob, out, M, D, D);
}

// Round 8
// 306.472 us; speedup vs baseline: 1.0535x; 1.0534x over previous
//
#include <hip/hip_runtime.h>
#include <hip/hip_bf16.h>
#include <math.h>

typedef __attribute__((ext_vector_type(8))) short short8;
typedef __attribute__((ext_vector_type(4))) short short4v;
typedef __attribute__((ext_vector_type(4))) float f32x4;
typedef unsigned short ushort_t;

__device__ __forceinline__ ushort_t f2bf(float f) {
    union { float f; unsigned u; } v; v.f = f;
    unsigned r = v.u + 0x7FFF + ((v.u >> 16) & 1);
    return (ushort_t)(r >> 16);
}
__device__ __forceinline__ float bf2f(short s) {
    union { unsigned u; float f; } v; v.u = ((unsigned)(ushort_t)s) << 16;
    return v.f;
}

// ---------------- fused fp32->bf16 convert: x | wq | wk | wv | wo -> contiguous bf16 ----------------
__global__ void cvt_all(const float* __restrict__ x,
                        const float* __restrict__ w0, const float* __restrict__ w1,
                        const float* __restrict__ w2, const float* __restrict__ w3,
                        ushort_t* __restrict__ dst, int md8, int dd8) {
    int i = blockIdx.x * blockDim.x + threadIdx.x;
    int stride = gridDim.x * blockDim.x;
    const int total = md8 + 4 * dd8;
    for (; i < total; i += stride) {
        const float* src;
        long off;
        if (i < md8) { src = x; off = i; }
        else {
            int j = i - md8;
            int which = j / dd8;
            off = j - (long)which * dd8;
            src = (which == 0) ? w0 : (which == 1) ? w1 : (which == 2) ? w2 : w3;
        }
        const float4* s = reinterpret_cast<const float4*>(src) + off * 2;
        float4 a = s[0], b = s[1];
        short8 o;
        o[0] = (short)f2bf(a.x); o[1] = (short)f2bf(a.y);
        o[2] = (short)f2bf(a.z); o[3] = (short)f2bf(a.w);
        o[4] = (short)f2bf(b.x); o[5] = (short)f2bf(b.y);
        o[6] = (short)f2bf(b.z); o[7] = (short)f2bf(b.w);
        reinterpret_cast<short8*>(dst)[i] = o;
    }
}

// ============ 256x256 8-phase GEMM (QKV) + fused RoPE + transposed-V epilogue ============
// Main loop identical to round 7 (0 bank conflicts verified). Epilogue:
//  - which<2 (Q,K): RoPE in-register: pairs (2i,2i+1) live in adjacent lanes (same row)
//    -> __shfl_xor(v,1) + fc/fs gather, store head-packed [which][bh][s][d].
//  - which==2 (V): store TRANSPOSED [bh][d][s]; 4 acc rows are s-consecutive -> one 8B store.
__global__ __launch_bounds__(512, 2) void gemm256_qkv(const ushort_t* __restrict__ A,
                                                      const ushort_t* __restrict__ Bw,
                                                      ushort_t* __restrict__ Cout,
                                                      ushort_t* __restrict__ Vt,
                                                      const float* __restrict__ fc,
                                                      const float* __restrict__ fs,
                                                      int M, int N, int K) {
    extern __shared__ __align__(16) ushort_t lds[];
    ushort_t* As = lds;              // 32768 elems
    ushort_t* Bs = lds + 32768;
    const int t = threadIdx.x;
    const int wid = t >> 6, lane = t & 63;
    const int wr = wid >> 2, wc = wid & 3;
    const int lr = lane & 15, lg = lane >> 4;

    const int ntc = N >> 8;
    const int nwg = (M >> 8) * ntc;
    const int bid = blockIdx.y * gridDim.x + blockIdx.x;
    const int cpx = nwg >> 3;
    const int swz = (bid & 7) * cpx + (bid >> 3);
    const int m0 = (swz / ntc) * 256, n0 = (swz % ntc) * 256;

    f32x4 acc[8][4] = {};

    const int r0 = t >> 3;
    const int c0 = (t & 7) ^ (r0 & 7);
    const ushort_t* gA = A + (long)(m0 + r0) * K + c0 * 8;
    const ushort_t* gB = Bw + (long)(n0 + r0) * K + c0 * 8;

    int aoffE[2];
    aoffE[0] = lr * 64 + (((0 + lg) ^ (lr & 7)) << 3);
    aoffE[1] = lr * 64 + (((4 + lg) ^ (lr & 7)) << 3);

    const int nt = K >> 6;   // 32 (even)

#define STAGE_A(X, h) do { const int p_ = (X) & 1;                                             \
    __builtin_amdgcn_global_load_lds((const __attribute__((address_space(1))) unsigned int*)   \
        (gA + (long)((h) * 128) * K + (X) * 64),                                               \
        (__attribute__((address_space(3))) unsigned int*)(As + (p_ * 2 + (h)) * 8192 + t * 8), \
        16, 0, 0);                                                                             \
    __builtin_amdgcn_global_load_lds((const __attribute__((address_space(1))) unsigned int*)   \
        (gA + (long)((h) * 128 + 64) * K + (X) * 64),                                          \
        (__attribute__((address_space(3))) unsigned int*)(As + (p_ * 2 + (h)) * 8192 + 4096 + t * 8), \
        16, 0, 0); } while (0)

#define STAGE_B(X, h) do { const int p_ = (X) & 1;                                             \
    __builtin_amdgcn_global_load_lds((const __attribute__((address_space(1))) unsigned int*)   \
        (gB + (long)((h) * 128) * K + (X) * 64),                                               \
        (__attribute__((address_space(3))) unsigned int*)(Bs + (p_ * 2 + (h)) * 8192 + t * 8), \
        16, 0, 0);                                                                             \
    __builtin_amdgcn_global_load_lds((const __attribute__((address_space(1))) unsigned int*)   \
        (gB + (long)((h) * 128 + 64) * K + (X) * 64),                                          \
        (__attribute__((address_space(3))) unsigned int*)(Bs + (p_ * 2 + (h)) * 8192 + 4096 + t * 8), \
        16, 0, 0); } while (0)

#define MIDSYNC() do {                                             \
    asm volatile("" ::: "memory");                                 \
    __builtin_amdgcn_s_barrier();                                  \
    asm volatile("s_waitcnt lgkmcnt(0)" ::: "memory");             \
    __builtin_amdgcn_sched_barrier(0); } while (0)

#define ENDBAR() do {                                              \
    asm volatile("" ::: "memory");                                 \
    __builtin_amdgcn_s_barrier(); } while (0)

#define MFMA_Q(AROW, BCOL, AR, BR) do {                            \
    __builtin_amdgcn_s_setprio(1);                                 \
    _Pragma("unroll")                                              \
    for (int ks = 0; ks < 2; ++ks)                                 \
        _Pragma("unroll")                                          \
        for (int m = 0; m < 4; ++m)                                \
            _Pragma("unroll")                                      \
            for (int n = 0; n < 2; ++n)                            \
                acc[(AROW) + m][(BCOL) + n] =                      \
                    __builtin_amdgcn_mfma_f32_16x16x32_bf16((AR)[m][ks], (BR)[n][ks], acc[(AROW) + m][(BCOL) + n], 0, 0, 0); \
    __builtin_amdgcn_s_setprio(0); } while (0)

#define KTILE(U, BUF) do {                                                                     \
    const int Asb = ((BUF) * 2 + wr) * 8192;                                                   \
    const int Bcb = ((BUF) * 2 + (wc >> 1)) * 8192 + (wc & 1) * 4096;                          \
    _Pragma("unroll")                                                                          \
    for (int m = 0; m < 4; ++m)                                                                \
        _Pragma("unroll")                                                                      \
        for (int ks = 0; ks < 2; ++ks)                                                         \
            ar[m][ks] = *reinterpret_cast<const short8*>(&As[Asb + m * 1024 + aoffE[ks]]);     \
    _Pragma("unroll")                                                                          \
    for (int n = 0; n < 2; ++n)                                                                \
        _Pragma("unroll")                                                                      \
        for (int ks = 0; ks < 2; ++ks)                                                         \
            br0[n][ks] = *reinterpret_cast<const short8*>(&Bs[Bcb + n * 1024 + aoffE[ks]]);    \
    if ((U) + 1 < nt) STAGE_A((U) + 1, 1);                                                     \
    MIDSYNC();                                                                                 \
    MFMA_Q(0, 0, ar, br0);                                                                     \
    ENDBAR();                                                                                  \
    _Pragma("unroll")                                                                          \
    for (int n = 0; n < 2; ++n)                                                                \
        _Pragma("unroll")                                                                      \
        for (int ks = 0; ks < 2; ++ks)                                                         \
            br1[n][ks] = *reinterpret_cast<const short8*>(&Bs[Bcb + 2048 + n * 1024 + aoffE[ks]]); \
    MIDSYNC();                                                                                 \
    MFMA_Q(0, 2, ar, br1);                                                                     \
    ENDBAR();                                                                                  \
    _Pragma("unroll")                                                                          \
    for (int m = 0; m < 4; ++m)                                                                \
        _Pragma("unroll")                                                                      \
        for (int ks = 0; ks < 2; ++ks)                                                         \
            ar[m][ks] = *reinterpret_cast<const short8*>(&As[Asb + 4096 + m * 1024 + aoffE[ks]]); \
    if ((U) + 2 < nt) STAGE_B((U) + 2, 0);                                                     \
    MIDSYNC();                                                                                 \
    MFMA_Q(4, 2, ar, br1);                                                                     \
    ENDBAR();                                                                                  \
    if ((U) + 2 < nt) { STAGE_A((U) + 2, 0); STAGE_B((U) + 2, 1); }                            \
    asm volatile("" ::: "memory");                                                             \
    __builtin_amdgcn_s_barrier();                                                              \
    MFMA_Q(4, 0, ar, br0);                                                                     \
    if ((U) < nt - 2) {                                                                        \
        asm volatile("s_waitcnt vmcnt(6)" ::: "memory");                                       \
    } else if ((U) == nt - 2) {                                                                \
        asm volatile("s_waitcnt vmcnt(0)" ::: "memory");                                       \
    }                                                                                          \
    __builtin_amdgcn_s_barrier(); } while (0)

    STAGE_A(0, 0); STAGE_A(0, 1); STAGE_B(0, 0); STAGE_B(0, 1);
    STAGE_A(1, 0); STAGE_B(1, 0); STAGE_B(1, 1);
    asm volatile("s_waitcnt vmcnt(6)" ::: "memory");
    __builtin_amdgcn_s_barrier();

    short8 ar[4][2], br0[2][2], br1[2][2];

    for (int U = 0; U < nt; U += 2) {
        KTILE(U, 0);
        KTILE(U + 1, 1);
    }
#undef KTILE
#undef MFMA_Q
#undef ENDBAR
#undef MIDSYNC
#undef STAGE_A
#undef STAGE_B

    // ---- fused epilogue ----
    const int S = 2048;
    #pragma unroll
    for (int m = 0; m < 8; ++m) {
        #pragma unroll
        for (int n = 0; n < 4; ++n) {
            const int col = n0 + wc * 64 + n * 16 + lr;
            const int which = col >> 11;          // wave-uniform (16-col group inside one 2048-block)
            const int h = (col >> 7) & 15;
            const int d = col & 127;
            const int rowb = m0 + wr * 128 + m * 16 + lg * 4;
            const int bb = rowb >> 11;
            const int sb = rowb & 2047;
            if (which == 2) {
                // V: transposed store [bh][d][s], 4 consecutive s -> one 8B store
                short4v o;
                #pragma unroll
                for (int r = 0; r < 4; ++r) o[r] = (short)f2bf(acc[m][n][r]);
                *reinterpret_cast<short4v*>(Vt + ((long)(bb * 16 + h) * 128 + d) * S + sb) = o;
            } else {
                // Q/K: RoPE then head-packed store
                const int i0 = d >> 1;
                #pragma unroll
                for (int r = 0; r < 4; ++r) {
                    const int s = sb + r;
                    float v = acc[m][n][r];
                    float p = __shfl_xor(v, 1);
                    float c  = fc[(long)s * 64 + i0];
                    float sn = fs[(long)s * 64 + i0];
                    float o = (lr & 1) ? (p * sn + v * c) : (v * c - p * sn);
                    Cout[(long)which * M * 2048 + (((long)(bb * 16 + h)) * 2048 + s) * 128 + d] = f2bf(o);
                }
            }
        }
    }
}

// ---------------- GEMM NT 128x128 (proven 2-phase dbuf) — used for wo ----------------
__global__ __launch_bounds__(256) void gemm_nt_f32(const ushort_t* __restrict__ A,
                                                   const ushort_t* __restrict__ Bw,
                                                   float* __restrict__ Cout,
                                                   int M, int N, int K) {
    __shared__ __align__(16) ushort_t As[2 * 128 * 32];
    __shared__ __align__(16) ushort_t Bs[2 * 128 * 32];
    const int t = threadIdx.x;
    const int wid = t >> 6, lane = t & 63;
    const int wm = wid >> 1, wn = wid & 1;
    const int lr = lane & 15, lg = lane >> 4;

    const int ntc = N >> 7;
    const int nwg = (M >> 7) * ntc;
    const int bid = blockIdx.y * gridDim.x + blockIdx.x;
    const int cpx = nwg >> 3;
    const int swz = (bid & 7) * cpx + (bid >> 3);
    const int m0 = (swz / ntc) * 128, n0 = (swz % ntc) * 128;

    f32x4 acc[4][4] = {};

    const int sh0 = wid * 1024 + lane * 8;
    const int sh1 = sh0 + 512;
    const int r0 = sh0 >> 5, c0 = sh0 & 31;
    const int r1 = sh1 >> 5, c1 = sh1 & 31;

    const ushort_t* gA0 = A + (long)(m0 + r0) * K + c0;
    const ushort_t* gA1 = A + (long)(m0 + r1) * K + c1;
    const ushort_t* gB0 = Bw + (long)(n0 + r0) * K + c0;
    const ushort_t* gB1 = Bw + (long)(n0 + r1) * K + c1;

    auto stage = [&](int k0, int nb) {
        ushort_t* as = As + nb * 4096;
        ushort_t* bs = Bs + nb * 4096;
        __builtin_amdgcn_global_load_lds((const __attribute__((address_space(1))) unsigned int*)(gA0 + k0),
                                         (__attribute__((address_space(3))) unsigned int*)(as + sh0), 16, 0, 0);
        __builtin_amdgcn_global_load_lds((const __attribute__((address_space(1))) unsigned int*)(gA1 + k0),
                                         (__attribute__((address_space(3))) unsigned int*)(as + sh1), 16, 0, 0);
        __builtin_amdgcn_global_load_lds((const __attribute__((address_space(1))) unsigned int*)(gB0 + k0),
                                         (__attribute__((address_space(3))) unsigned int*)(bs + sh0), 16, 0, 0);
        __builtin_amdgcn_global_load_lds((const __attribute__((address_space(1))) unsigned int*)(gB1 + k0),
                                         (__attribute__((address_space(3))) unsigned int*)(bs + sh1), 16, 0, 0);
    };

    const int nt = K >> 5;
    stage(0, 0);
    __syncthreads();
    int cur = 0;

    for (int ti = 0; ti < nt; ++ti) {
        if (ti + 1 < nt) stage((ti + 1) << 5, cur ^ 1);
        const ushort_t* as = As + cur * 4096;
        const ushort_t* bs = Bs + cur * 4096;
        short8 af[4], bfr[4];
        #pragma unroll
        for (int m = 0; m < 4; ++m)
            af[m] = *reinterpret_cast<const short8*>(&as[(wm * 64 + m * 16 + lr) * 32 + lg * 8]);
        #pragma unroll
        for (int n = 0; n < 4; ++n)
            bfr[n] = *reinterpret_cast<const short8*>(&bs[(wn * 64 + n * 16 + lr) * 32 + lg * 8]);
        #pragma unroll
        for (int m = 0; m < 4; ++m)
            #pragma unroll
            for (int n = 0; n < 4; ++n)
                acc[m][n] = __builtin_amdgcn_mfma_f32_16x16x32_bf16(af[m], bfr[n], acc[m][n], 0, 0, 0);
        __syncthreads();
        cur ^= 1;
    }

    #pragma unroll
    for (int m = 0; m < 4; ++m) {
        #pragma unroll
        for (int n = 0; n < 4; ++n) {
            const int col = n0 + wn * 64 + n * 16 + lr;
            #pragma unroll
            for (int r = 0; r < 4; ++r) {
                const int row = m0 + wm * 64 + m * 16 + lg * 4 + r;
                Cout[(long)row * N + col] = acc[m][n][r];
            }
        }
    }
}

// ---------------- causal flash attention (folded, T14 async-STAGE K/V) ----------------
__global__ __launch_bounds__(256, 3) void attn_kernel(const ushort_t* __restrict__ Qp,
                                                      const ushort_t* __restrict__ Kp,
                                                      const ushort_t* __restrict__ Vtg,
                                                      ushort_t* __restrict__ O,
                                                      int S, int H) {
    __shared__ __align__(16) ushort_t Ks[64][136];
    __shared__ __align__(16) ushort_t Vs[128][72];
    __shared__ __align__(16) ushort_t Pl[4][16][72];
    const int t = threadIdx.x, wid = t >> 6, lane = t & 63;
    const int lr = lane & 15, lg = lane >> 4;
    const int bh = blockIdx.y;
    const int b = bh / H, h = bh % H;
    const ushort_t* Qh = Qp + (long)bh * S * 128;
    const ushort_t* Kh = Kp + (long)bh * S * 128;
    const ushort_t* Vth = Vtg + (long)bh * 128 * S;
    const int nq = S / 64;
    const float scale = 0.08838834764831845f;

    const int ksr = t >> 2;
    const int ksc = (t & 3) * 32;
    const int vsr = t & 127;
    const int vsc = (t >> 7) * 32;

    for (int qsel = 0; qsel < 2; ++qsel) {
        const int qt = qsel ? (nq - 1 - blockIdx.x) : blockIdx.x;
        const int qb0 = qt * 64;

        const int qrow = qb0 + wid * 16 + lr;
        short8 qf[4];
        #pragma unroll
        for (int kk = 0; kk < 4; ++kk)
            qf[kk] = *reinterpret_cast<const short8*>(Qh + (long)qrow * 128 + kk * 32 + lg * 8);

        f32x4 oacc[8] = {};
        float mrow[4], lsum[4];
        #pragma unroll
        for (int r = 0; r < 4; ++r) { mrow[r] = -INFINITY; lsum[r] = 0.f; }

        const int nkt = qt + 1;

        short8 kreg[4], vreg[4];
        {
            const ushort_t* kgp = Kh + t * 32;
            const ushort_t* vgp = Vth + (long)vsr * S + vsc;
            #pragma unroll
            for (int j = 0; j < 4; ++j) kreg[j] = *reinterpret_cast<const short8*>(kgp + j * 8);
            #pragma unroll
            for (int j = 0; j < 4; ++j) vreg[j] = *reinterpret_cast<const short8*>(vgp + j * 8);
        }

        for (int kt = 0; kt < nkt; ++kt) {
            const int kv0 = kt * 64;
            __syncthreads();
            #pragma unroll
            for (int j = 0; j < 4; ++j)
                *reinterpret_cast<short8*>(&Ks[ksr][ksc + j * 8]) = kreg[j];
            #pragma unroll
            for (int j = 0; j < 4; ++j)
                *reinterpret_cast<short8*>(&Vs[vsr][vsc + j * 8]) = vreg[j];
            __syncthreads();
            if (kt + 1 < nkt) {
                const ushort_t* kgp = Kh + (long)(kv0 + 64) * 128 + t * 32;
                const ushort_t* vgp = Vth + (long)vsr * S + kv0 + 64 + vsc;
                #pragma unroll
                for (int j = 0; j < 4; ++j) kreg[j] = *reinterpret_cast<const short8*>(kgp + j * 8);
                #pragma unroll
                for (int j = 0; j < 4; ++j) vreg[j] = *reinterpret_cast<const short8*>(vgp + j * 8);
            }

            f32x4 sacc[4] = {};
            #pragma unroll
            for (int kk = 0; kk < 4; ++kk) {
                #pragma unroll
                for (int n = 0; n < 4; ++n) {
                    short8 kf = *reinterpret_cast<const short8*>(&Ks[n * 16 + lr][kk * 32 + lg * 8]);
                    sacc[n] = __builtin_amdgcn_mfma_f32_16x16x32_bf16(qf[kk], kf, sacc[n], 0, 0, 0);
                }
            }
            float sv[4][4];
            const int myq = qb0 + wid * 16 + lg * 4;
            #pragma unroll
            for (int n = 0; n < 4; ++n) {
                int kcol = kv0 + n * 16 + lr;
                #pragma unroll
                for (int r = 0; r < 4; ++r) {
                    float xv = sacc[n][r] * scale;
                    sv[n][r] = (kcol > myq + r) ? -1e9f : xv;
                }
            }
            float alpha[4];
            #pragma unroll
            for (int r = 0; r < 4; ++r) {
                float mx = fmaxf(fmaxf(sv[0][r], sv[1][r]), fmaxf(sv[2][r], sv[3][r]));
                #pragma unroll
                for (int off = 1; off < 16; off <<= 1)
                    mx = fmaxf(mx, __shfl_xor(mx, off));
                float mnew = fmaxf(mrow[r], mx);
                alpha[r] = __expf(mrow[r] - mnew);
                float ts = 0.f;
                #pragma unroll
                for (int n = 0; n < 4; ++n) {
                    float p = __expf(sv[n][r] - mnew);
                    sv[n][r] = p;
                    ts += p;
                }
                #pragma unroll
                for (int off = 1; off < 16; off <<= 1)
                    ts += __shfl_xor(ts, off);
                lsum[r] = lsum[r] * alpha[r] + ts;
                mrow[r] = mnew;
            }
            #pragma unroll
            for (int f = 0; f < 8; ++f)
                #pragma unroll
                for (int r = 0; r < 4; ++r)
                    oacc[f][r] *= alpha[r];
            #pragma unroll
            for (int n = 0; n < 4; ++n)
                #pragma unroll
                for (int r = 0; r < 4; ++r)
                    Pl[wid][lg * 4 + r][n * 16 + lr] = f2bf(sv[n][r]);
            __asm volatile("" ::: "memory");
            short8 pf[2];
            #pragma unroll
            for (int ks = 0; ks < 2; ++ks)
                pf[ks] = *reinterpret_cast<const short8*>(&Pl[wid][lr][ks * 32 + lg * 8]);
            #pragma unroll
            for (int ks = 0; ks < 2; ++ks) {
                #pragma unroll
                for (int f = 0; f < 8; ++f) {
                    short8 vf = *reinterpret_cast<const short8*>(&Vs[f * 16 + lr][ks * 32 + lg * 8]);
                    oacc[f] = __builtin_amdgcn_mfma_f32_16x16x32_bf16(pf[ks], vf, oacc[f], 0, 0, 0);
                }
            }
        }
        float inv[4];
        #pragma unroll
        for (int r = 0; r < 4; ++r) inv[r] = 1.f / lsum[r];
        ushort_t* Oh = O + (long)b * S * 2048 + h * 128;
        #pragma unroll
        for (int f = 0; f < 8; ++f) {
            #pragma unroll
            for (int r = 0; r < 4; ++r) {
                int row = qb0 + wid * 16 + lg * 4 + r;
                int col = f * 16 + lr;
                Oh[(long)row * 2048 + col] = f2bf(oacc[f][r] * inv[r]);
            }
        }
    }
}

extern "C" void kernel_launch(void* const* d_in, const int* in_sizes, int n_in,
                              void* d_out, int out_size, void* d_ws, size_t ws_size,
                              hipStream_t stream) {
    const float* x  = (const float*)d_in[0];
    const float* fc = (const float*)d_in[1];
    const float* fs = (const float*)d_in[2];
    const float* wq = (const float*)d_in[3];
    const float* wk = (const float*)d_in[4];
    const float* wv = (const float*)d_in[5];
    const float* wo = (const float*)d_in[6];
    float* out = (float*)d_out;

    const int B = 2, S = 2048, D = 2048, H = 16;
    const int M = B * S;            // 4096
    const size_t MD = (size_t)M * D;
    const size_t DD = (size_t)D * D;

    char* ws = (char*)d_ws;
    ushort_t* xbf = (ushort_t*)ws;                  // A input; attnb overlay after GEMM
    ushort_t* wqb = (ushort_t*)(ws + MD * 2);       // wq|wk|wv|wo bf16 contiguous
    ushort_t* wob = wqb + 3 * DD;
    ushort_t* qp  = wqb + 4 * DD;                   // Q packed [bh,s,128]
    ushort_t* kp  = qp + MD;                        // K packed
    ushort_t* vtg = kp + MD;                        // V transposed [bh,128,s] (direct from epilogue)
    ushort_t* attnb = xbf;                          // overlay: x dead after QKV GEMM

    // 1) single fused convert (x + 4 weights; dst regions contiguous)
    cvt_all<<<2048, 256, 0, stream>>>(x, wq, wk, wv, wo, xbf, (int)(MD / 8), (int)(DD / 8));

    // 2) fused QKV projection + RoPE + transposed-V epilogue
    dim3 gq(6144 / 256, M / 256);
    gemm256_qkv<<<gq, 512, 131072, stream>>>(xbf, wqb, qp, vtg, fc, fs, M, 3 * D, D);

    // 3) causal flash attention
    dim3 ga(S / 128, B * H);
    attn_kernel<<<ga, 256, 0, stream>>>(qp, kp, vtg, attnb, S, H);

    // 4) output projection (fp32 out)
    dim3 gg(D / 128, M / 128);
    gemm_nt_f32<<<gg, 256, 0, stream>>>(attnb, wob, out, M, D, D);
}